// Round 8
// baseline (211.348 us; speedup 1.0000x reference)
//
#include <hip/hip_runtime.h>
#include <stdint.h>

// MHA forward. I/O = fp32 (reference dtype); internal compute = bf16 MFMA.
// Pipeline (4 kernels):
//   prep:     cvt X->bf16 | transpose+cvt W_qkv (W_q pre-scaled) | W_o
//   gemm_qkv: qkv = X @ Wqkv^T  (BK=64, XOR-swizzled LDS, XCD-chunked grid;
//             V-blocks emit V^T via padded-LDS transpose)
//   attn_fwd: causal flash attention. 512-thr = 2 kv-groups x 4 waves, one
//             64-row q-tile per block; per-group DOUBLE-BUFFERED K/V with
//             ONE __syncthreads per superstep (stage-next issued BEFORE
//             compute -> the barrier's implicit vmcnt(0) drain is free).
//   gemm_o:   out = ctx @ Wo^T  (128x128 tile, XCD-chunked grid, fp32 out)
//
// Round history (rocprof-driven):
//   R1: reg-staged prefetch spilled -> staging stays global_load_lds.
//       XCD-resident attn bh map kept (FETCH 68->22->12 MB).
//   R3: __syncthreads drains vmcnt -> counted prefetch never engaged.
//   R4: raw-barrier counted vmcnt @ 12-wave occupancy = neutral.
//   R5: (512,6) VGPR cap -> spill (VGPR 40, 135/181 MB scratch) -> 107us.
//   R6: (512,4) fixed spill; occ 33%, attn 40.5us, VALU 41% / Mfma 16%.
//   R7: loop-invariant staging ptrs + gemm_o 128^2; attn < 40us (below
//       top-5 cutoff). R8: halve attn barriers via group dbuf (the R4
//       pipeline at R6 occupancy); T1 XCD swizzle on both GEMMs.
//
// Verified layout facts (learn_hip m89/m91/m97/m120):
//   A-operand: lane holds A[m=lane&15][k=(lane>>4)*8+j], j=0..7
//   B-operand: lane holds B[k=(lane>>4)*8+j][n=lane&15]   (same map as A)
//   C/D:       col=lane&15, row=(lane>>4)*4+reg
//   global_load_lds: wave-uniform LDS base + lane*16, size=16.

typedef __attribute__((ext_vector_type(8))) short bf16x8;
typedef __attribute__((ext_vector_type(4))) float f32x4;

#define LOG2E 1.44269504088896340736f
#define QSCALE (0.125f * LOG2E) /* 1/sqrt(64) * log2(e), folded into W_q */

__device__ __forceinline__ unsigned short f2b(float f) {
  union { float f; unsigned int i; } x; x.f = f;
  unsigned int i = x.i;
  return (unsigned short)((i + 0x7FFFu + ((i >> 16) & 1u)) >> 16);
}

__device__ __forceinline__ void async16(const void* g, void* l) {
  __builtin_amdgcn_global_load_lds(
      (__attribute__((address_space(1))) void*)g,
      (__attribute__((address_space(3))) void*)l, 16, 0, 0);
}

__device__ __forceinline__ f32x4 mfma16(bf16x8 a, bf16x8 b, f32x4 c) {
  return __builtin_amdgcn_mfma_f32_16x16x32_bf16(a, b, c, 0, 0, 0);
}

__device__ __forceinline__ unsigned int fbits(float f) {
  union { float f; unsigned int i; } x; x.f = f;
  return x.i;
}

// ------------------------------------------------------------------- prep
__global__ __launch_bounds__(256) void prep(
    const float* __restrict__ X, const float* __restrict__ Wqkv,
    const float* __restrict__ Wo, unsigned short* __restrict__ Xb,
    unsigned short* __restrict__ WqkvT, unsigned short* __restrict__ WoT) {
  __shared__ __align__(16) unsigned short Lt[64 * 64];
  const int bx = blockIdx.x;
  const int t = threadIdx.x;
  if (bx < 2048) {
    const size_t i = ((size_t)bx * 256 + t) * 8;
    float4 a = *(const float4*)(X + i);
    float4 b = *(const float4*)(X + i + 4);
    unsigned short e[8];
    e[0] = f2b(a.x); e[1] = f2b(a.y); e[2] = f2b(a.z); e[3] = f2b(a.w);
    e[4] = f2b(b.x); e[5] = f2b(b.y); e[6] = f2b(b.z); e[7] = f2b(b.w);
    *(uint4*)(Xb + i) = *(const uint4*)e;
    return;
  }
  const bool is_qkv = (bx < 2816);
  const int bid = is_qkv ? bx - 2048 : bx - 2816;
  const float* src = is_qkv ? Wqkv : Wo;
  unsigned short* dst = is_qkv ? WqkvT : WoT;
  const int Ccols = is_qkv ? 3072 : 1024;
  const int r0 = (bid & 15) * 64, c0 = (bid >> 4) * 64;
  const float s = (is_qkv && c0 < 1024) ? QSCALE : 1.0f;
#pragma unroll
  for (int it = 0; it < 4; ++it) {
    int c = it * 256 + t;
    int sr = c >> 4, co = (c & 15) * 4;
    float4 v = *(const float4*)(src + (size_t)(r0 + sr) * Ccols + c0 + co);
    Lt[(co + 0) * 64 + sr] = f2b(v.x * s);
    Lt[(co + 1) * 64 + sr] = f2b(v.y * s);
    Lt[(co + 2) * 64 + sr] = f2b(v.z * s);
    Lt[(co + 3) * 64 + sr] = f2b(v.w * s);
  }
  __syncthreads();
#pragma unroll
  for (int it = 0; it < 2; ++it) {
    int c = it * 256 + t;
    int dr = c >> 3, so = (c & 7) * 8;
    *(uint4*)(dst + (size_t)(c0 + dr) * 1024 + r0 + so) =
        *(const uint4*)(Lt + dr * 64 + so);
  }
}

// ---------------------------------------------------------------- gemm_qkv
// 128x128 tile, BK=64, XOR-swizzled LDS. R8: XCD-chunked grid remap —
// each XCD owns 96 consecutive remapped ids = 4 full m-rows x 24 n:
// A panels 1 MB fully L2-resident (was: all 32 m-panels = 8 MB thrash).
__global__ __launch_bounds__(256) void gemm_qkv(
    const unsigned short* __restrict__ A, const unsigned short* __restrict__ Bt,
    unsigned short* __restrict__ C, unsigned short* __restrict__ Vt) {
  constexpr int K = 1024, N = 3072;
  __shared__ __align__(16) unsigned short Sm[16896];  // 33792 B
  unsigned short* As = Sm;          // 128*64
  unsigned short* Bs = Sm + 8192;   // 128*64
  unsigned short* Lt = Sm;          // 128*132 (epilogue only)

  const int t = threadIdx.x;
  const int w = t >> 6, l = t & 63;
  // bijective XCD chunk swizzle: 768 blocks, 96 per XCD
  const int flat = blockIdx.x + 24 * blockIdx.y;
  const int swz = (flat & 7) * 96 + (flat >> 3);
  const int m0 = (swz / 24) * 128, n0 = (swz % 24) * 128;
  const int wm = (w >> 1) * 64, wn = (w & 1) * 64;
  const int lrow = l & 15, lq = l >> 4;

  f32x4 acc[4][4] = {};

  for (int k0 = 0; k0 < K; k0 += 64) {
    __syncthreads();
#pragma unroll
    for (int r = 0; r < 4; ++r) {
      const int c = r * 256 + t;
      const int row = c >> 3;
      const int so = ((c & 7) ^ (row & 7)) * 8;
      async16(A + (size_t)(m0 + row) * K + k0 + so,
              As + (size_t)(r * 256 + t) * 8);
      async16(Bt + (size_t)(n0 + row) * K + k0 + so,
              Bs + (size_t)(r * 256 + t) * 8);
    }
    asm volatile("s_waitcnt vmcnt(0)" ::: "memory");
    __syncthreads();

#pragma unroll
    for (int kh = 0; kh < 2; ++kh) {
      bf16x8 af[4], bf[4];
      const int phys = ((kh * 4 + lq) ^ (lrow & 7)) * 8;
#pragma unroll
      for (int i = 0; i < 4; ++i)
        af[i] = *(const bf16x8*)(As + (wm + i * 16 + lrow) * 64 + phys);
#pragma unroll
      for (int j = 0; j < 4; ++j)
        bf[j] = *(const bf16x8*)(Bs + (wn + j * 16 + lrow) * 64 + phys);
#pragma unroll
      for (int i = 0; i < 4; ++i)
#pragma unroll
        for (int j = 0; j < 4; ++j)
          acc[i][j] = mfma16(af[i], bf[j], acc[i][j]);
    }
  }

  if (n0 < 2048) {  // Q/K blocks: plain store into qkv
#pragma unroll
    for (int i = 0; i < 4; ++i)
#pragma unroll
      for (int j = 0; j < 4; ++j)
#pragma unroll
        for (int r = 0; r < 4; ++r) {
          int gr = m0 + wm + i * 16 + lq * 4 + r;
          int gc = n0 + wn + j * 16 + lrow;
          C[(size_t)gr * N + gc] = f2b(acc[i][j][r]);
        }
  } else {  // V blocks: transpose through padded LDS -> coalesced Vt stores
    __syncthreads();  // all waves done reading As/Bs
#pragma unroll
    for (int i = 0; i < 4; ++i)
#pragma unroll
      for (int j = 0; j < 4; ++j) {
        int col_loc = wn + j * 16 + lrow;   // V column within tile
        int row_loc = wm + i * 16 + lq * 4; // token within tile
        uint2 pk;
        pk.x = (unsigned int)f2b(acc[i][j][0]) |
               ((unsigned int)f2b(acc[i][j][1]) << 16);
        pk.y = (unsigned int)f2b(acc[i][j][2]) |
               ((unsigned int)f2b(acc[i][j][3]) << 16);
        *(uint2*)(Lt + col_loc * 132 + row_loc) = pk;
      }
    __syncthreads();
    const int b = m0 >> 11, s0 = m0 & 2047;
    const int vb0 = n0 - 2048;
#pragma unroll
    for (int rnd = 0; rnd < 8; ++rnd) {
      int vrow = rnd * 16 + (t >> 4);  // V col within tile
      int sloc = (t & 15) * 8;
      int vcol = vb0 + vrow;
      int bh = b * 16 + (vcol >> 6);
      int d = vcol & 63;
      *(uint4*)(Vt + ((size_t)bh * 64 + d) * 2048 + s0 + sloc) =
          *(const uint4*)(Lt + vrow * 132 + sloc);
    }
  }
}

// ------------------------- out-proj GEMM: 128x128 tile, BK=64, XCD-chunked
__global__ __launch_bounds__(256) void gemm_o(
    const unsigned short* __restrict__ A, const unsigned short* __restrict__ Bt,
    float* __restrict__ C, int M, int N, int K) {
  __shared__ __align__(16) unsigned short As[128 * 64];
  __shared__ __align__(16) unsigned short Bs[128 * 64];
  const int t = threadIdx.x;
  const int w = t >> 6, l = t & 63;
  // bijective XCD chunk swizzle: 256 blocks, 32 per XCD (A 1MB + B 2MB resident)
  const int flat = blockIdx.x + 8 * blockIdx.y;
  const int swz = (flat & 7) * 32 + (flat >> 3);
  const int m0 = (swz >> 3) * 128, n0 = (swz & 7) * 128;
  const int wm = (w >> 1) * 64, wn = (w & 1) * 64;
  const int lrow = l & 15, lq = l >> 4;

  f32x4 acc[4][4] = {};

  for (int k0 = 0; k0 < K; k0 += 64) {
    __syncthreads();
#pragma unroll
    for (int r = 0; r < 4; ++r) {
      const int c = r * 256 + t;
      const int row = c >> 3;
      const int so = ((c & 7) ^ (row & 7)) * 8;
      async16(A + (size_t)(m0 + row) * K + k0 + so,
              As + (size_t)(r * 256 + t) * 8);
      async16(Bt + (size_t)(n0 + row) * K + k0 + so,
              Bs + (size_t)(r * 256 + t) * 8);
    }
    asm volatile("s_waitcnt vmcnt(0)" ::: "memory");
    __syncthreads();

#pragma unroll
    for (int kh = 0; kh < 2; ++kh) {
      bf16x8 af[4], bf[4];
      const int phys = ((kh * 4 + lq) ^ (lrow & 7)) * 8;
#pragma unroll
      for (int i = 0; i < 4; ++i)
        af[i] = *(const bf16x8*)(As + (wm + i * 16 + lrow) * 64 + phys);
#pragma unroll
      for (int j = 0; j < 4; ++j)
        bf[j] = *(const bf16x8*)(Bs + (wn + j * 16 + lrow) * 64 + phys);
#pragma unroll
      for (int i = 0; i < 4; ++i)
#pragma unroll
        for (int j = 0; j < 4; ++j)
          acc[i][j] = mfma16(af[i], bf[j], acc[i][j]);
    }
  }

#pragma unroll
  for (int i = 0; i < 4; ++i)
#pragma unroll
    for (int j = 0; j < 4; ++j)
#pragma unroll
      for (int r = 0; r < 4; ++r) {
        int gr = m0 + wm + i * 16 + lq * 4 + r;
        int gc = n0 + wn + j * 16 + lrow;
        C[(size_t)gr * N + gc] = acc[i][j][r];
      }
}

// ---------------------------------------------------------------- attention
// R8: 512 threads = 2 kv-groups x 4 waves; one 64-row q-tile per block.
// Per-group DOUBLE-BUFFERED K/V: each superstep = {issue next-tile stage
// into buf[p^1] -> compute buf[p] -> __syncthreads}. ONE barrier per
// superstep (was 2); its implicit vmcnt(0) drains loads that had the whole
// compute phase to land (issue-before-compute => drain is free).
// Sync proof: the single end barrier orders (a) reads of buf[p] before
// next iter's staging overwrite of buf[p], and (b) stage-writes to
// buf[p^1] (drained by barrier's vmcnt(0)) before next iter's reads.
// Grid (32 bh, 32 ti): xcd = bh&7 (4 bh x 768 KB < 4 MiB L2);
// ti = 31-blockIdx.y heavy-first. LDS 73 KB -> 2 blocks/CU = 16-wave cap
// (>= measured ~10.6 actual). (512,4): VGPR cap 128 (R5 lesson).
__global__ __launch_bounds__(512, 4) void attn_fwd(
    const unsigned short* __restrict__ qkv,
    const unsigned short* __restrict__ Vt,
    unsigned short* __restrict__ ctx) {
  __shared__ __align__(16) unsigned short Ks[2][2][64 * 64];  // [group][par]
  __shared__ __align__(16) unsigned short Vs[2][2][64 * 64];
  __shared__ __align__(16) unsigned short Ps[8][16 * 72];

  const int bh = blockIdx.x;       // xcd = bh & 7 (L2 residency)
  const int ti = 31 - blockIdx.y;  // heavy-first
  const int b = bh >> 4, h = bh & 15;
  const int t = threadIdx.x;
  const int g = t >> 8;    // kv-group
  const int tl = t & 255;  // id within group
  const int w = tl >> 6;   // wave within group = q row strip
  const int gw = t >> 6;   // global wave id (P buffer)
  const int l = t & 63;
  const int lm = l & 15, lq = l >> 4;
  const int sw = lm & 7;
  const int c0 = (lq ^ sw) * 8;
  const int c1 = ((lq + 4) ^ sw) * 8;

  const unsigned short* Qp = qkv + (size_t)(b * 2048) * 3072 + h * 64;
  const unsigned short* Kp = qkv + (size_t)(b * 2048) * 3072 + 1024 + h * 64;
  const unsigned short* Vb = Vt + (size_t)bh * 64 * 2048;

  const int qrow = ti * 64 + w * 16 + lm;
  bf16x8 qf0 = *(const bf16x8*)(Qp + (size_t)qrow * 3072 + lq * 8);
  bf16x8 qf1 = *(const bf16x8*)(Qp + (size_t)qrow * 3072 + 32 + lq * 8);

  // loop-invariant staging source pointers (group's tile kt = g first);
  // stride per superstep: K +128 rows, V +128 cols.
  const int srow = tl >> 3, scp = tl & 7;
  const int sso = (scp ^ (srow & 7)) * 8;  // (srow+32)&7 == srow&7
  const unsigned short* kp0 = Kp + (size_t)(g * 64 + srow) * 3072 + sso;
  const unsigned short* kp1 = kp0 + (size_t)32 * 3072;
  const unsigned short* vp0 = Vb + (size_t)srow * 2048 + g * 64 + sso;
  const unsigned short* vp1 = vp0 + (size_t)32 * 2048;
  // wave-uniform LDS dst bases (parity selected at issue: +4096 shorts)
  unsigned short* kd0 = Ks[g][0] + (size_t)(w * 64) * 8;
  unsigned short* kd1 = Ks[g][0] + (size_t)(256 + w * 64) * 8;
  unsigned short* vd0 = Vs[g][0] + (size_t)(w * 64) * 8;
  unsigned short* vd1 = Vs[g][0] + (size_t)(256 + w * 64) * 8;

  f32x4 oacc[4] = {};
  float lsum = 0.f;

  const int nsup = (ti >> 1) + 1;  // supersteps: kt = 2*jj + g <= ti

  // prologue: stage tile kt=g into parity 0 (guard: group may have no work)
  if (g <= ti) {
    async16(kp0, kd0);
    async16(vp0, vd0);
    async16(kp1, kd1);
    async16(vp1, vd1);
    kp0 += 128 * 3072; kp1 += 128 * 3072;
    vp0 += 128; vp1 += 128;
  }
  __syncthreads();  // implicit vmcnt(0): tile 0 landed block-wide

  for (int jj = 0; jj < nsup; ++jj) {
    const int p = jj & 1;
    const int kt = 2 * jj + g;

    if (kt + 2 <= ti) {  // issue next tile into buf[p^1] BEFORE compute
      const int po = (p ^ 1) * 4096;  // 64*64 shorts per buffer
      async16(kp0, kd0 + po);
      async16(vp0, vd0 + po);
      async16(kp1, kd1 + po);
      async16(vp1, vd1 + po);
      kp0 += 128 * 3072; kp1 += 128 * 3072;
      vp0 += 128; vp1 += 128;
    }

    if (kt <= ti) {
      const unsigned short* Kc = Ks[g][p];
      const unsigned short* Vc = Vs[g][p];

      // hoist V fragments: vf[ks*4+nt]
      bf16x8 vf[8];
#pragma unroll
      for (int nt = 0; nt < 4; ++nt) {
        const unsigned short* vr = Vc + (nt * 16 + lm) * 64;
        vf[nt] = *(const bf16x8*)(vr + c0);
        vf[4 + nt] = *(const bf16x8*)(vr + c1);
      }

      // S^T = K Q^T : lane holds q = lm, kv = mt*16 + lq*4 + r
      f32x4 sacc[4] = {};
      __builtin_amdgcn_s_setprio(1);
#pragma unroll
      for (int mt = 0; mt < 4; ++mt) {
        const unsigned short* kr = Kc + (mt * 16 + lm) * 64;
        bf16x8 bk0 = *(const bf16x8*)(kr + c0);
        bf16x8 bk1 = *(const bf16x8*)(kr + c1);
        sacc[mt] = mfma16(bk0, qf0, sacc[mt]);
        sacc[mt] = mfma16(bk1, qf1, sacc[mt]);
      }
      __builtin_amdgcn_s_setprio(0);

      const bool diag = (kt == ti);
      const int qloc = w * 16 + lm;
#pragma unroll
      for (int mt = 0; mt < 4; ++mt) {
        float p0 = __builtin_amdgcn_exp2f(sacc[mt][0]);
        float p1 = __builtin_amdgcn_exp2f(sacc[mt][1]);
        float p2 = __builtin_amdgcn_exp2f(sacc[mt][2]);
        float p3 = __builtin_amdgcn_exp2f(sacc[mt][3]);
        if (diag) {
          const int kvb = mt * 16 + lq * 4;
          if (kvb + 0 > qloc) p0 = 0.f;
          if (kvb + 1 > qloc) p1 = 0.f;
          if (kvb + 2 > qloc) p2 = 0.f;
          if (kvb + 3 > qloc) p3 = 0.f;
        }
        lsum += (p0 + p1) + (p2 + p3);
        uint2 pk;
        pk.x = (fbits(p1) & 0xFFFF0000u) | (fbits(p0) >> 16);
        pk.y = (fbits(p3) & 0xFFFF0000u) | (fbits(p2) >> 16);
        *(uint2*)(&Ps[gw][lm * 72 + mt * 16 + lq * 4]) = pk;
      }
      asm volatile("s_waitcnt lgkmcnt(0)" ::: "memory");

      // O += P V
      __builtin_amdgcn_s_setprio(1);
#pragma unroll
      for (int ks = 0; ks < 2; ++ks) {
        bf16x8 pa = *(const bf16x8*)(&Ps[gw][lm * 72 + ks * 32 + lq * 8]);
#pragma unroll
        for (int nt = 0; nt < 4; ++nt)
          oacc[nt] = mfma16(pa, vf[ks * 4 + nt], oacc[nt]);
      }
      __builtin_amdgcn_s_setprio(0);
    }

    __syncthreads();  // single barrier/superstep: drains next-tile loads
                      // (issued pre-compute) + orders buf reuse
  }

  // reduce per-lane row sums across the 4 lane groups
  lsum += __shfl_xor(lsum, 16, 64);
  lsum += __shfl_xor(lsum, 32, 64);

  // cross-group combine: group 1 parks partials in LDS, group 0 finalizes
  float* fbuf = (float*)Ks;  // 64x64 fp32 = 16 KB (Ks block is 32 KB)
  float* lbuf = (float*)Ps;  // 64 fp32
  if (g == 1) {
#pragma unroll
    for (int nt = 0; nt < 4; ++nt)
#pragma unroll
      for (int r = 0; r < 4; ++r)
        fbuf[(w * 16 + lq * 4 + r) * 64 + nt * 16 + lm] = oacc[nt][r];
    if (l < 16) lbuf[w * 16 + lm] = lsum;
  }
  __syncthreads();
  if (g == 0) {
    const float ltot = lsum + lbuf[w * 16 + lm];
    float rinv[4];
#pragma unroll
    for (int r = 0; r < 4; ++r)
      rinv[r] = 1.f / __shfl(ltot, lq * 4 + r, 64);
#pragma unroll
    for (int nt = 0; nt < 4; ++nt)
#pragma unroll
      for (int r = 0; r < 4; ++r) {
        float v = oacc[nt][r] +
                  fbuf[(w * 16 + lq * 4 + r) * 64 + nt * 16 + lm];
        size_t tok = (size_t)b * 2048 + ti * 64 + w * 16 + lq * 4 + r;
        ctx[tok * 1024 + h * 64 + nt * 16 + lm] = f2b(v * rinv[r]);
      }
  }
}

// ---------------------------------------------------------------- launch
extern "C" void kernel_launch(void* const* d_in, const int* in_sizes, int n_in,
                              void* d_out, int out_size, void* d_ws,
                              size_t ws_size, hipStream_t stream) {
  const float* query = (const float*)d_in[0];
  // d_in[1] key, d_in[2] value: unused by reference. d_in[3] mask: causal
  // tril, applied analytically.
  const float* w_qkv = (const float*)d_in[4];
  const float* w_o = (const float*)d_in[5];
  float* out = (float*)d_out;

  unsigned short* ws = (unsigned short*)d_ws;
  unsigned short* wqkvT = ws;                               // 3072*1024
  unsigned short* woT = wqkvT + (size_t)3072 * 1024;        // 1024*1024
  unsigned short* Xb = woT + (size_t)1024 * 1024;           // 4096*1024
  unsigned short* qkv = Xb + (size_t)4096 * 1024;           // 4096*3072 (Q,K)
  unsigned short* Vt = qkv + (size_t)4096 * 3072;           // 32*64*2048
  unsigned short* ctx = Xb;  // Xb dead after gemm_qkv -> reuse for ctx
  // total: 48 MB of d_ws

  prep<<<dim3(3072), 256, 0, stream>>>(query, w_qkv, w_o, Xb, wqkvT, woT);
  gemm_qkv<<<dim3(24, 32), 256, 0, stream>>>(Xb, wqkvT, qkv, Vt);
  attn_fwd<<<dim3(32, 32), 512, 0, stream>>>(qkv, Vt, ctx);
  gemm_o<<<dim3(8, 32), 256, 0, stream>>>(ctx, woT, out, 4096, 1024, 1024);
}

// Round 9
// 196.482 us; speedup vs baseline: 1.0757x; 1.0757x over previous
//
#include <hip/hip_runtime.h>
#include <stdint.h>

// MHA forward. I/O = fp32 (reference dtype); internal compute = bf16 MFMA.
// Pipeline (4 kernels):
//   prep:     cvt X->bf16 | transpose+cvt W_qkv (W_q pre-scaled) | W_o
//   gemm_qkv: qkv = X @ Wqkv^T  (BK=64, XOR-swizzled LDS, XCD-chunked grid;
//             V-blocks emit V^T via padded-LDS transpose)
//   attn_fwd: causal flash attention (R7 structure: 512-thr = 2 kv-groups
//             x 4 waves, one 64-row q-tile/block, single-buffered staging,
//             loop-invariant pointers, 50 KB LDS -> 3 blocks/CU)
//   gemm_o:   out = ctx @ Wo^T  (128x128 tile, XCD-chunked grid, fp32 out)
//
// Round history (rocprof-driven):
//   R1: reg-staged prefetch spilled -> staging stays global_load_lds.
//       XCD-resident attn bh map kept (FETCH 68->22->12 MB).
//   R3: __syncthreads drains vmcnt -> counted prefetch never engaged.
//   R4: raw-barrier counted vmcnt @ 12-wave occupancy = neutral.
//   R5: (512,6) VGPR cap -> spill -> 107us. R6: (512,4) fixed; occ 33%.
//   R7: loop-invariant ptrs + gemm_o 128^2; attn ~38-40us.
//   R8: attn group-dbuf = 82 KB LDS -> 1 block/CU -> 54us REGRESSION
//       (occupancy >> barrier count). GEMM XCD swizzle gained ~7us (attn
//       +15 but total only +7.7). R9: revert attn to R7, keep GEMM swz.
//
// Verified layout facts (learn_hip m89/m91/m97/m120):
//   A-operand: lane holds A[m=lane&15][k=(lane>>4)*8+j], j=0..7
//   B-operand: lane holds B[k=(lane>>4)*8+j][n=lane&15]   (same map as A)
//   C/D:       col=lane&15, row=(lane>>4)*4+reg
//   global_load_lds: wave-uniform LDS base + lane*16, size=16.

typedef __attribute__((ext_vector_type(8))) short bf16x8;
typedef __attribute__((ext_vector_type(4))) float f32x4;

#define LOG2E 1.44269504088896340736f
#define QSCALE (0.125f * LOG2E) /* 1/sqrt(64) * log2(e), folded into W_q */

__device__ __forceinline__ unsigned short f2b(float f) {
  union { float f; unsigned int i; } x; x.f = f;
  unsigned int i = x.i;
  return (unsigned short)((i + 0x7FFFu + ((i >> 16) & 1u)) >> 16);
}

__device__ __forceinline__ void async16(const void* g, void* l) {
  __builtin_amdgcn_global_load_lds(
      (__attribute__((address_space(1))) void*)g,
      (__attribute__((address_space(3))) void*)l, 16, 0, 0);
}

__device__ __forceinline__ f32x4 mfma16(bf16x8 a, bf16x8 b, f32x4 c) {
  return __builtin_amdgcn_mfma_f32_16x16x32_bf16(a, b, c, 0, 0, 0);
}

__device__ __forceinline__ unsigned int fbits(float f) {
  union { float f; unsigned int i; } x; x.f = f;
  return x.i;
}

// ------------------------------------------------------------------- prep
__global__ __launch_bounds__(256) void prep(
    const float* __restrict__ X, const float* __restrict__ Wqkv,
    const float* __restrict__ Wo, unsigned short* __restrict__ Xb,
    unsigned short* __restrict__ WqkvT, unsigned short* __restrict__ WoT) {
  __shared__ __align__(16) unsigned short Lt[64 * 64];
  const int bx = blockIdx.x;
  const int t = threadIdx.x;
  if (bx < 2048) {
    const size_t i = ((size_t)bx * 256 + t) * 8;
    float4 a = *(const float4*)(X + i);
    float4 b = *(const float4*)(X + i + 4);
    unsigned short e[8];
    e[0] = f2b(a.x); e[1] = f2b(a.y); e[2] = f2b(a.z); e[3] = f2b(a.w);
    e[4] = f2b(b.x); e[5] = f2b(b.y); e[6] = f2b(b.z); e[7] = f2b(b.w);
    *(uint4*)(Xb + i) = *(const uint4*)e;
    return;
  }
  const bool is_qkv = (bx < 2816);
  const int bid = is_qkv ? bx - 2048 : bx - 2816;
  const float* src = is_qkv ? Wqkv : Wo;
  unsigned short* dst = is_qkv ? WqkvT : WoT;
  const int Ccols = is_qkv ? 3072 : 1024;
  const int r0 = (bid & 15) * 64, c0 = (bid >> 4) * 64;
  const float s = (is_qkv && c0 < 1024) ? QSCALE : 1.0f;
#pragma unroll
  for (int it = 0; it < 4; ++it) {
    int c = it * 256 + t;
    int sr = c >> 4, co = (c & 15) * 4;
    float4 v = *(const float4*)(src + (size_t)(r0 + sr) * Ccols + c0 + co);
    Lt[(co + 0) * 64 + sr] = f2b(v.x * s);
    Lt[(co + 1) * 64 + sr] = f2b(v.y * s);
    Lt[(co + 2) * 64 + sr] = f2b(v.z * s);
    Lt[(co + 3) * 64 + sr] = f2b(v.w * s);
  }
  __syncthreads();
#pragma unroll
  for (int it = 0; it < 2; ++it) {
    int c = it * 256 + t;
    int dr = c >> 3, so = (c & 7) * 8;
    *(uint4*)(dst + (size_t)(c0 + dr) * 1024 + r0 + so) =
        *(const uint4*)(Lt + dr * 64 + so);
  }
}

// ---------------------------------------------------------------- gemm_qkv
// 128x128 tile, BK=64, XOR-swizzled LDS, XCD-chunked grid (R8: ~7us win —
// each XCD owns 4 full m-rows x 24 n: A panels 1 MB fully L2-resident).
__global__ __launch_bounds__(256) void gemm_qkv(
    const unsigned short* __restrict__ A, const unsigned short* __restrict__ Bt,
    unsigned short* __restrict__ C, unsigned short* __restrict__ Vt) {
  constexpr int K = 1024, N = 3072;
  __shared__ __align__(16) unsigned short Sm[16896];  // 33792 B
  unsigned short* As = Sm;          // 128*64
  unsigned short* Bs = Sm + 8192;   // 128*64
  unsigned short* Lt = Sm;          // 128*132 (epilogue only)

  const int t = threadIdx.x;
  const int w = t >> 6, l = t & 63;
  // bijective XCD chunk swizzle: 768 blocks, 96 per XCD
  const int flat = blockIdx.x + 24 * blockIdx.y;
  const int swz = (flat & 7) * 96 + (flat >> 3);
  const int m0 = (swz / 24) * 128, n0 = (swz % 24) * 128;
  const int wm = (w >> 1) * 64, wn = (w & 1) * 64;
  const int lrow = l & 15, lq = l >> 4;

  f32x4 acc[4][4] = {};

  for (int k0 = 0; k0 < K; k0 += 64) {
    __syncthreads();
#pragma unroll
    for (int r = 0; r < 4; ++r) {
      const int c = r * 256 + t;
      const int row = c >> 3;
      const int so = ((c & 7) ^ (row & 7)) * 8;
      async16(A + (size_t)(m0 + row) * K + k0 + so,
              As + (size_t)(r * 256 + t) * 8);
      async16(Bt + (size_t)(n0 + row) * K + k0 + so,
              Bs + (size_t)(r * 256 + t) * 8);
    }
    asm volatile("s_waitcnt vmcnt(0)" ::: "memory");
    __syncthreads();

#pragma unroll
    for (int kh = 0; kh < 2; ++kh) {
      bf16x8 af[4], bf[4];
      const int phys = ((kh * 4 + lq) ^ (lrow & 7)) * 8;
#pragma unroll
      for (int i = 0; i < 4; ++i)
        af[i] = *(const bf16x8*)(As + (wm + i * 16 + lrow) * 64 + phys);
#pragma unroll
      for (int j = 0; j < 4; ++j)
        bf[j] = *(const bf16x8*)(Bs + (wn + j * 16 + lrow) * 64 + phys);
#pragma unroll
      for (int i = 0; i < 4; ++i)
#pragma unroll
        for (int j = 0; j < 4; ++j)
          acc[i][j] = mfma16(af[i], bf[j], acc[i][j]);
    }
  }

  if (n0 < 2048) {  // Q/K blocks: plain store into qkv
#pragma unroll
    for (int i = 0; i < 4; ++i)
#pragma unroll
      for (int j = 0; j < 4; ++j)
#pragma unroll
        for (int r = 0; r < 4; ++r) {
          int gr = m0 + wm + i * 16 + lq * 4 + r;
          int gc = n0 + wn + j * 16 + lrow;
          C[(size_t)gr * N + gc] = f2b(acc[i][j][r]);
        }
  } else {  // V blocks: transpose through padded LDS -> coalesced Vt stores
    __syncthreads();  // all waves done reading As/Bs
#pragma unroll
    for (int i = 0; i < 4; ++i)
#pragma unroll
      for (int j = 0; j < 4; ++j) {
        int col_loc = wn + j * 16 + lrow;   // V column within tile
        int row_loc = wm + i * 16 + lq * 4; // token within tile
        uint2 pk;
        pk.x = (unsigned int)f2b(acc[i][j][0]) |
               ((unsigned int)f2b(acc[i][j][1]) << 16);
        pk.y = (unsigned int)f2b(acc[i][j][2]) |
               ((unsigned int)f2b(acc[i][j][3]) << 16);
        *(uint2*)(Lt + col_loc * 132 + row_loc) = pk;
      }
    __syncthreads();
    const int b = m0 >> 11, s0 = m0 & 2047;
    const int vb0 = n0 - 2048;
#pragma unroll
    for (int rnd = 0; rnd < 8; ++rnd) {
      int vrow = rnd * 16 + (t >> 4);  // V col within tile
      int sloc = (t & 15) * 8;
      int vcol = vb0 + vrow;
      int bh = b * 16 + (vcol >> 6);
      int d = vcol & 63;
      *(uint4*)(Vt + ((size_t)bh * 64 + d) * 2048 + s0 + sloc) =
          *(const uint4*)(Lt + vrow * 132 + sloc);
    }
  }
}

// ------------------------- out-proj GEMM: 128x128 tile, BK=64, XCD-chunked
__global__ __launch_bounds__(256) void gemm_o(
    const unsigned short* __restrict__ A, const unsigned short* __restrict__ Bt,
    float* __restrict__ C, int M, int N, int K) {
  __shared__ __align__(16) unsigned short As[128 * 64];
  __shared__ __align__(16) unsigned short Bs[128 * 64];
  const int t = threadIdx.x;
  const int w = t >> 6, l = t & 63;
  // bijective XCD chunk swizzle: 256 blocks, 32 per XCD (A 1MB + B 2MB resident)
  const int flat = blockIdx.x + 8 * blockIdx.y;
  const int swz = (flat & 7) * 32 + (flat >> 3);
  const int m0 = (swz >> 3) * 128, n0 = (swz & 7) * 128;
  const int wm = (w >> 1) * 64, wn = (w & 1) * 64;
  const int lrow = l & 15, lq = l >> 4;

  f32x4 acc[4][4] = {};

  for (int k0 = 0; k0 < K; k0 += 64) {
    __syncthreads();
#pragma unroll
    for (int r = 0; r < 4; ++r) {
      const int c = r * 256 + t;
      const int row = c >> 3;
      const int so = ((c & 7) ^ (row & 7)) * 8;
      async16(A + (size_t)(m0 + row) * K + k0 + so,
              As + (size_t)(r * 256 + t) * 8);
      async16(Bt + (size_t)(n0 + row) * K + k0 + so,
              Bs + (size_t)(r * 256 + t) * 8);
    }
    asm volatile("s_waitcnt vmcnt(0)" ::: "memory");
    __syncthreads();

#pragma unroll
    for (int kh = 0; kh < 2; ++kh) {
      bf16x8 af[4], bf[4];
      const int phys = ((kh * 4 + lq) ^ (lrow & 7)) * 8;
#pragma unroll
      for (int i = 0; i < 4; ++i)
        af[i] = *(const bf16x8*)(As + (wm + i * 16 + lrow) * 64 + phys);
#pragma unroll
      for (int j = 0; j < 4; ++j)
        bf[j] = *(const bf16x8*)(Bs + (wn + j * 16 + lrow) * 64 + phys);
#pragma unroll
      for (int i = 0; i < 4; ++i)
#pragma unroll
        for (int j = 0; j < 4; ++j)
          acc[i][j] = mfma16(af[i], bf[j], acc[i][j]);
    }
  }

#pragma unroll
  for (int i = 0; i < 4; ++i)
#pragma unroll
    for (int j = 0; j < 4; ++j)
#pragma unroll
      for (int r = 0; r < 4; ++r) {
        int gr = m0 + wm + i * 16 + lq * 4 + r;
        int gc = n0 + wn + j * 16 + lrow;
        C[(size_t)gr * N + gc] = acc[i][j][r];
      }
}

// ---------------------------------------------------------------- attention
// R9 = R7 attn (best measured): 512 threads = 2 kv-groups x 4 waves; one
// 64-row q-tile per block. Group g handles kv tiles kt = g, g+2, ...
// Grid (32 bh, 32 ti): xcd = bh&7 (4 bh x 768 KB < 4 MiB L2);
// ti = 31-blockIdx.y heavy-first. LDS 50 KB -> 3 blocks/CU = 24-wave cap.
// (512,4): VGPR cap 128 (R5 lesson: (512,6) spilled).
// Single-buffered staging, loop-invariant source pointers (R7).
// R8 lesson: group-dbuf costs 32 KB LDS -> 1 block/CU -> regression;
// occupancy dominates barrier count in this kernel.
__global__ __launch_bounds__(512, 4) void attn_fwd(
    const unsigned short* __restrict__ qkv,
    const unsigned short* __restrict__ Vt,
    unsigned short* __restrict__ ctx) {
  __shared__ __align__(16) unsigned short Ks[2][64 * 64];
  __shared__ __align__(16) unsigned short Vs[2][64 * 64];
  __shared__ __align__(16) unsigned short Ps[8][16 * 72];

  const int bh = blockIdx.x;       // xcd = bh & 7 (L2 residency)
  const int ti = 31 - blockIdx.y;  // heavy-first
  const int b = bh >> 4, h = bh & 15;
  const int t = threadIdx.x;
  const int g = t >> 8;    // kv-group
  const int tl = t & 255;  // id within group
  const int w = tl >> 6;   // wave within group = q row strip
  const int gw = t >> 6;   // global wave id (P buffer)
  const int l = t & 63;
  const int lm = l & 15, lq = l >> 4;
  const int sw = lm & 7;
  const int c0 = (lq ^ sw) * 8;
  const int c1 = ((lq + 4) ^ sw) * 8;

  const unsigned short* Qp = qkv + (size_t)(b * 2048) * 3072 + h * 64;
  const unsigned short* Kp = qkv + (size_t)(b * 2048) * 3072 + 1024 + h * 64;
  const unsigned short* Vb = Vt + (size_t)bh * 64 * 2048;

  const int qrow = ti * 64 + w * 16 + lm;
  bf16x8 qf0 = *(const bf16x8*)(Qp + (size_t)qrow * 3072 + lq * 8);
  bf16x8 qf1 = *(const bf16x8*)(Qp + (size_t)qrow * 3072 + 32 + lq * 8);

  // loop-invariant staging addresses: per-thread source pointers for this
  // group's first tile (kt = g); stride per superstep is constant.
  const int srow = tl >> 3, scp = tl & 7;
  const int sso = (scp ^ (srow & 7)) * 8;  // (srow+32)&7 == srow&7
  const unsigned short* kp0 = Kp + (size_t)(g * 64 + srow) * 3072 + sso;
  const unsigned short* kp1 = kp0 + (size_t)32 * 3072;
  const unsigned short* vp0 = Vb + (size_t)srow * 2048 + g * 64 + sso;
  const unsigned short* vp1 = vp0 + (size_t)32 * 2048;
  unsigned short* kd0 = Ks[g] + (size_t)(w * 64) * 8;
  unsigned short* kd1 = Ks[g] + (size_t)(256 + w * 64) * 8;
  unsigned short* vd0 = Vs[g] + (size_t)(w * 64) * 8;
  unsigned short* vd1 = Vs[g] + (size_t)(256 + w * 64) * 8;

  f32x4 oacc[4] = {};
  float lsum = 0.f;

  const int nsup = (ti >> 1) + 1;  // supersteps: kt = 2*jj + g <= ti

  for (int jj = 0; jj < nsup; ++jj) {
    const int kt = 2 * jj + g;
    const bool have = (kt <= ti);
    __syncthreads();  // protect group buffers from overwrite
    if (have) {
      async16(kp0, kd0);
      async16(vp0, vd0);
      async16(kp1, kd1);
      async16(vp1, vd1);
    }
    kp0 += 128 * 3072; kp1 += 128 * 3072;  // 2 tiles ahead (group stride)
    vp0 += 128; vp1 += 128;
    asm volatile("s_waitcnt vmcnt(0)" ::: "memory");
    __syncthreads();
    if (!have) continue;

    const unsigned short* Kc = Ks[g];
    const unsigned short* Vc = Vs[g];

    // hoist V fragments: vf[ks*4+nt] (overlaps with softmax VALU)
    bf16x8 vf[8];
#pragma unroll
    for (int nt = 0; nt < 4; ++nt) {
      const unsigned short* vr = Vc + (nt * 16 + lm) * 64;
      vf[nt] = *(const bf16x8*)(vr + c0);
      vf[4 + nt] = *(const bf16x8*)(vr + c1);
    }

    // S^T = K Q^T : lane holds q = lm, kv = mt*16 + lq*4 + r
    f32x4 sacc[4] = {};
    __builtin_amdgcn_s_setprio(1);
#pragma unroll
    for (int mt = 0; mt < 4; ++mt) {
      const unsigned short* kr = Kc + (mt * 16 + lm) * 64;
      bf16x8 bk0 = *(const bf16x8*)(kr + c0);
      bf16x8 bk1 = *(const bf16x8*)(kr + c1);
      sacc[mt] = mfma16(bk0, qf0, sacc[mt]);
      sacc[mt] = mfma16(bk1, qf1, sacc[mt]);
    }
    __builtin_amdgcn_s_setprio(0);

    const bool diag = (kt == ti);
    const int qloc = w * 16 + lm;
#pragma unroll
    for (int mt = 0; mt < 4; ++mt) {
      float p0 = __builtin_amdgcn_exp2f(sacc[mt][0]);
      float p1 = __builtin_amdgcn_exp2f(sacc[mt][1]);
      float p2 = __builtin_amdgcn_exp2f(sacc[mt][2]);
      float p3 = __builtin_amdgcn_exp2f(sacc[mt][3]);
      if (diag) {
        const int kvb = mt * 16 + lq * 4;
        if (kvb + 0 > qloc) p0 = 0.f;
        if (kvb + 1 > qloc) p1 = 0.f;
        if (kvb + 2 > qloc) p2 = 0.f;
        if (kvb + 3 > qloc) p3 = 0.f;
      }
      lsum += (p0 + p1) + (p2 + p3);
      uint2 pk;
      pk.x = (fbits(p1) & 0xFFFF0000u) | (fbits(p0) >> 16);
      pk.y = (fbits(p3) & 0xFFFF0000u) | (fbits(p2) >> 16);
      *(uint2*)(&Ps[gw][lm * 72 + mt * 16 + lq * 4]) = pk;
    }
    asm volatile("s_waitcnt lgkmcnt(0)" ::: "memory");

    // O += P V  (A = P from Ps, B = V frags in regs)
    __builtin_amdgcn_s_setprio(1);
#pragma unroll
    for (int ks = 0; ks < 2; ++ks) {
      bf16x8 pa = *(const bf16x8*)(&Ps[gw][lm * 72 + ks * 32 + lq * 8]);
#pragma unroll
      for (int nt = 0; nt < 4; ++nt)
        oacc[nt] = mfma16(pa, vf[ks * 4 + nt], oacc[nt]);
    }
    __builtin_amdgcn_s_setprio(0);
  }

  // reduce per-lane row sums across the 4 lane groups -> all lanes hold
  // the sum for q = w*16 + lm
  lsum += __shfl_xor(lsum, 16, 64);
  lsum += __shfl_xor(lsum, 32, 64);

  // cross-group combine: group 1 parks partials in LDS, group 0 finalizes
  __syncthreads();
  float* fbuf = (float*)Ks;  // 64x64 fp32 = 16 KB (Ks block is 16 KB)
  float* lbuf = (float*)Ps;  // 64 fp32
  if (g == 1) {
#pragma unroll
    for (int nt = 0; nt < 4; ++nt)
#pragma unroll
      for (int r = 0; r < 4; ++r)
        fbuf[(w * 16 + lq * 4 + r) * 64 + nt * 16 + lm] = oacc[nt][r];
    if (l < 16) lbuf[w * 16 + lm] = lsum;
  }
  __syncthreads();
  if (g == 0) {
    const float ltot = lsum + lbuf[w * 16 + lm];
    float rinv[4];
#pragma unroll
    for (int r = 0; r < 4; ++r)
      rinv[r] = 1.f / __shfl(ltot, lq * 4 + r, 64);
#pragma unroll
    for (int nt = 0; nt < 4; ++nt)
#pragma unroll
      for (int r = 0; r < 4; ++r) {
        float v = oacc[nt][r] +
                  fbuf[(w * 16 + lq * 4 + r) * 64 + nt * 16 + lm];
        size_t tok = (size_t)b * 2048 + ti * 64 + w * 16 + lq * 4 + r;
        ctx[tok * 1024 + h * 64 + nt * 16 + lm] = f2b(v * rinv[r]);
      }
  }
}

// ---------------------------------------------------------------- launch
extern "C" void kernel_launch(void* const* d_in, const int* in_sizes, int n_in,
                              void* d_out, int out_size, void* d_ws,
                              size_t ws_size, hipStream_t stream) {
  const float* query = (const float*)d_in[0];
  // d_in[1] key, d_in[2] value: unused by reference. d_in[3] mask: causal
  // tril, applied analytically.
  const float* w_qkv = (const float*)d_in[4];
  const float* w_o = (const float*)d_in[5];
  float* out = (float*)d_out;

  unsigned short* ws = (unsigned short*)d_ws;
  unsigned short* wqkvT = ws;                               // 3072*1024
  unsigned short* woT = wqkvT + (size_t)3072 * 1024;        // 1024*1024
  unsigned short* Xb = woT + (size_t)1024 * 1024;           // 4096*1024
  unsigned short* qkv = Xb + (size_t)4096 * 1024;           // 4096*3072 (Q,K)
  unsigned short* Vt = qkv + (size_t)4096 * 3072;           // 32*64*2048
  unsigned short* ctx = Xb;  // Xb dead after gemm_qkv -> reuse for ctx
  // total: 48 MB of d_ws

  prep<<<dim3(3072), 256, 0, stream>>>(query, w_qkv, w_o, Xb, wqkvT, woT);
  gemm_qkv<<<dim3(24, 32), 256, 0, stream>>>(Xb, wqkvT, qkv, Vt);
  attn_fwd<<<dim3(32, 32), 512, 0, stream>>>(qkv, Vt, ctx);
  gemm_o<<<dim3(8, 32), 256, 0, stream>>>(ctx, woT, out, 4096, 1024, 1024);
}